// Round 15
// baseline (191.524 us; speedup 1.0000x reference)
//
#include <hip/hip_runtime.h>
#include <hip/hip_bf16.h>
#include <math.h>

// Problem constants (fixed by the reference):
constexpr int Cc = 512;   // channels
constexpr int Hh = 8;     // heads
constexpr int Dd = 64;    // head dim
constexpr int Nn = 2048;  // kv length
constexpr int Bb = 8;     // batch
constexpr int GK = 512;   // K dim of every GEMM here

typedef __attribute__((ext_vector_type(8))) short short8;
typedef __attribute__((ext_vector_type(4))) float f32x4;
typedef __attribute__((ext_vector_type(4))) unsigned int u32x4;
typedef __attribute__((ext_vector_type(2))) unsigned int u32x2;

// scale * log2(e) folded into Q at projection time
#define C2SCALE 0.1803368801f

static __device__ __forceinline__ ushort f2bf(float v) {
  __hip_bfloat16 h = __float2bfloat16(v);
  return *reinterpret_cast<ushort*>(&h);
}
static __device__ __forceinline__ float bf2f(ushort u) {
  __hip_bfloat16 h = *reinterpret_cast<__hip_bfloat16*>(&u);
  return __bfloat162float(h);
}
// pack two f32 -> u32 of two bf16 (f0 low, f1 high), RNE via f2bf
static __device__ __forceinline__ unsigned int pk2(float f0, float f1) {
  return (unsigned int)f2bf(f0) | ((unsigned int)f2bf(f1) << 16);
}

// ---------------------------------------------------------------------------
// MFMA GEMM with fused dtype handling (unchanged, proven): C = A B^T (+bias).
// ---------------------------------------------------------------------------
template <int MODE, int TERMS, bool AF32, bool BF32>
__global__ __launch_bounds__(256) void mfma_nt2_kernel(
    const void* __restrict__ A0p, const void* __restrict__ A1p,
    const void* __restrict__ B0p, const void* __restrict__ B1p,
    const float* __restrict__ bias, float* __restrict__ Cf,
    ushort* __restrict__ Chi, int Nc)
{
  __shared__ ushort lAh[128 * 32];
  __shared__ ushort lBh[128 * 32];
  __shared__ ushort lAl[TERMS == 3 ? 128 * 32 : 1];
  __shared__ ushort lBl[TERMS == 3 ? 128 * 32 : 1];

  const int tid = threadIdx.x;
  const int w = tid >> 6, lane = tid & 63;
  const int c = lane & 15, g = lane >> 4;
  const int wr = (w >> 1) * 64, wc = (w & 1) * 64;
  const int m0 = blockIdx.y * 128, n0 = blockIdx.x * 128;
  const int sr = tid >> 2;          // staging row 0..63
  const int sk = (tid & 3) * 8;     // staging k-offset (elements)

  short8 rAh[2], rAl[2], rBh[2], rBl[2];

  auto ldf32 = [&](const float* F, size_t idx, short8& h, short8& l) {
    const float4 f0 = *(const float4*)(F + idx);
    const float4 f1 = *(const float4*)(F + idx + 4);
    const float vv[8] = {f0.x, f0.y, f0.z, f0.w, f1.x, f1.y, f1.z, f1.w};
#pragma unroll
    for (int j = 0; j < 8; ++j) {
      const ushort hb = f2bf(vv[j]);
      ((ushort*)&h)[j] = hb;
      if (TERMS == 3) ((ushort*)&l)[j] = f2bf(vv[j] - bf2f(hb));
    }
  };

  auto loadA = [&](int k0) {
#pragma unroll
    for (int hf = 0; hf < 2; ++hf) {
      const size_t idx = (size_t)(m0 + sr + hf * 64) * GK + k0 + sk;
      if (AF32) {
        ldf32((const float*)A0p, idx, rAh[hf], rAl[hf]);
      } else {
        rAh[hf] = *(const short8*)((const ushort*)A0p + idx);
        if (TERMS == 3) rAl[hf] = *(const short8*)((const ushort*)A1p + idx);
      }
    }
  };
  auto loadB = [&](int k0) {
#pragma unroll
    for (int hf = 0; hf < 2; ++hf) {
      const size_t idx = (size_t)(n0 + sr + hf * 64) * GK + k0 + sk;
      if (BF32) {
        ldf32((const float*)B0p, idx, rBh[hf], rBl[hf]);
      } else {
        rBh[hf] = *(const short8*)((const ushort*)B0p + idx);
        if (TERMS == 3) rBl[hf] = *(const short8*)((const ushort*)B1p + idx);
      }
    }
  };

  f32x4 acc[4][4] = {};
  loadA(0);
  loadB(0);

  for (int k0 = 0; k0 < GK; k0 += 32) {
    __syncthreads();
    *(short8*)&lAh[sr * 32 + sk]        = rAh[0];
    *(short8*)&lAh[(sr + 64) * 32 + sk] = rAh[1];
    *(short8*)&lBh[sr * 32 + sk]        = rBh[0];
    *(short8*)&lBh[(sr + 64) * 32 + sk] = rBh[1];
    if (TERMS == 3) {
      *(short8*)&lAl[sr * 32 + sk]        = rAl[0];
      *(short8*)&lAl[(sr + 64) * 32 + sk] = rAl[1];
      *(short8*)&lBl[sr * 32 + sk]        = rBl[0];
      *(short8*)&lBl[(sr + 64) * 32 + sk] = rBl[1];
    }
    __syncthreads();
    if (k0 + 32 < GK) { loadA(k0 + 32); loadB(k0 + 32); }  // T14 issue-early

    short8 ah[4], al[4], bh[4], bl[4];
#pragma unroll
    for (int i = 0; i < 4; ++i) {
      const int ar = (wr + i * 16 + c) * 32 + g * 8;
      const int br = (wc + i * 16 + c) * 32 + g * 8;
      ah[i] = *(const short8*)&lAh[ar];
      bh[i] = *(const short8*)&lBh[br];
      if (TERMS == 3) {
        al[i] = *(const short8*)&lAl[ar];
        bl[i] = *(const short8*)&lBl[br];
      }
    }
#pragma unroll
    for (int mi = 0; mi < 4; ++mi)
#pragma unroll
      for (int nj = 0; nj < 4; ++nj) {
        if (TERMS == 3) {
          acc[mi][nj] = __builtin_amdgcn_mfma_f32_16x16x32_bf16(ah[mi], bl[nj], acc[mi][nj], 0,0,0);
          acc[mi][nj] = __builtin_amdgcn_mfma_f32_16x16x32_bf16(al[mi], bh[nj], acc[mi][nj], 0,0,0);
        }
        acc[mi][nj] = __builtin_amdgcn_mfma_f32_16x16x32_bf16(ah[mi], bh[nj], acc[mi][nj], 0,0,0);
      }
  }

#pragma unroll
  for (int mi = 0; mi < 4; ++mi) {
#pragma unroll
    for (int r = 0; r < 4; ++r) {
      const size_t rb = (size_t)(m0 + wr + mi * 16 + g * 4 + r) * Nc;
#pragma unroll
      for (int nj = 0; nj < 4; ++nj) {
        const int col = n0 + wc + nj * 16 + c;
        const float v = acc[mi][nj][r];
        if (MODE == 0) {
          Cf[rb + col] = v + bias[col];
        } else if (MODE == 1) {
          Chi[rb + col] = f2bf(v);
        } else {
          Chi[rb + col] = f2bf(v * C2SCALE);   // Q pre-scaled for exp2 domain
        }
      }
    }
  }
}

// ---------------------------------------------------------------------------
// Swapped-operand MFMA flash attention, 16x16x32, 16 q-rows per wave,
// LANE-LOCAL P via sigma-permuted V. vs R14: the sigma permutation is now
// applied on the GLOBAL fetch side (two u32x2 loads per thread) so the LDS
// write is one linear ds_write_b128 — the R12-proven conflict-free shape
// (m173 pattern: pre-swizzle global source, keep LDS linear). LDS contents
// are bit-identical to R14; compute is unchanged.
// STATIC softmax in exp2 domain (Q pre-scaled); l-reduce deferred to epilogue.
// Block = 128 q-rows x 1 (b,h), 8 waves x 16 q-rows; 128-key staging chunks.
// ---------------------------------------------------------------------------
__global__ __launch_bounds__(512, 4) void attn_mfma11_kernel(
    const ushort* __restrict__ qhi,  // (TQ, C) bf16, pre-scaled by C2SCALE
    const ushort* __restrict__ kbf,  // (B*N, C) bf16
    const ushort* __restrict__ vtb,  // (C, B*N) bf16  (V^T)
    ushort* __restrict__ ohi,        // (TQ, C) bf16 hi
    ushort* __restrict__ olo)        // (TQ, C) bf16 lo
{
  // Q_LENGTHS = 1024 + 128*b ; cumulative offsets:
  constexpr int QOFF[8] = {0, 1024, 2176, 3456, 4864, 6400, 8064, 9856};

  const int lin = blockIdx.x;
  const int b  = lin & 7;            // lin%8=b -> batch pinned per XCD
  const int h  = (lin >> 3) & 7;
  const int qt = lin >> 6;

  const int Lb  = 1024 + 128 * b;
  const int off = QOFF[b];
  if (qt * 128 >= Lb) return;        // uniform; lengths are %128==0

  constexpr int KP = 72;             // K row stride (bf16): conflict-free class
  constexpr int VP = 136;            // V row stride (bf16): same class
  constexpr int NC = Nn / 128;       // 16 chunks of 128 keys
  __shared__ ushort Ks[128 * KP];    // [key][d]
  __shared__ ushort Vs[64 * VP];     // [d][sigma(key) within 128]

  const int tid = threadIdx.x;
  const int lane = tid & 63;
  const int w = tid >> 6;            // wave 0..7 -> q-rows [w*16, w*16+16)
  const int c = lane & 15;           // q (B-col) / key-row (A) / d-row (PV A)
  const int g = (lane >> 4) & 3;     // k-chunk selector

  // Q fragments: B-operand [n=q=c][k=d = ks2*32 + g*8 + j]
  short8 qf[2];
  const int qrow = off + qt * 128 + w * 16 + c;
  {
    const size_t base = (size_t)qrow * Cc + h * Dd + g * 8;
    qf[0] = *(const short8*)(qhi + base);
    qf[1] = *(const short8*)(qhi + base + 32);
  }

  float l_part = 0.f;                // per-lane partial sum; reduced at end
  f32x4 accO4[4] = {};               // O^T: [db] rows d=db*16+g*4+r, col q=c

  const size_t kbase = (size_t)b * Nn * Cc + h * Dd;
  const size_t vbase = (size_t)h * Dd * (Bb * Nn) + (size_t)b * Nn;

  for (int ch = 0; ch < NC; ++ch) {
    __syncthreads();   // previous chunk's LDS reads complete
    // stage K: 128 keys x 128B (2 short8 per thread, 512 threads)
#pragma unroll
    for (int it = 0; it < 2; ++it) {
      const int i = tid + it * 512;
      const int row = i >> 3, c8 = (i & 7) * 8;
      *(short8*)&Ks[row * KP + c8] =
          *(const short8*)&kbf[kbase + (size_t)(ch * 128 + row) * Cc + c8];
    }
    // stage V: linear b128 LDS write; sigma^-1 applied to the GLOBAL fetch.
    // LDS pos c8+p (p=0..7) holds key  (c8&~31) + (p>=4)*16 + ((c8>>3)&3)*4
    //                                + (p&3)  — identical contents to R14.
#pragma unroll
    for (int it = 0; it < 2; ++it) {
      const int i = tid + it * 512;
      const int row = i >> 4, c8 = (i & 15) * 8;
      const int kb1 = (c8 & ~31) | (((c8 >> 3) & 3) << 2);
      const size_t gb = vbase + (size_t)row * (Bb * Nn) + ch * 128;
      const u32x2 vlo = *(const u32x2*)&vtb[gb + kb1];
      const u32x2 vhi = *(const u32x2*)&vtb[gb + kb1 + 16];
      u32x4 vv;
      vv[0] = vlo[0]; vv[1] = vlo[1];
      vv[2] = vhi[0]; vv[3] = vhi[1];
      *(short8*)&Vs[row * VP + c8] = __builtin_bit_cast(short8, vv);
    }
    __syncthreads();

#pragma unroll
    for (int st = 0; st < 2; ++st) {
      // ---- S^T = K Q^T : accT4[kb][r] = S[key=st*64+kb*16+g*4+r][q=c] ----
      f32x4 accT4[4] = {};
      __builtin_amdgcn_s_setprio(1);
#pragma unroll
      for (int ks2 = 0; ks2 < 2; ++ks2) {
#pragma unroll
        for (int kb = 0; kb < 4; ++kb) {
          const short8 kf = *(const short8*)
              &Ks[(st * 64 + kb * 16 + c) * KP + ks2 * 32 + g * 8];
          accT4[kb] = __builtin_amdgcn_mfma_f32_16x16x32_bf16(kf, qf[ks2], accT4[kb], 0,0,0);
        }
      }
      __builtin_amdgcn_s_setprio(0);

      // ---- static softmax: P = exp2(S), pack to bf16 pairs (lane-local) ----
      unsigned int up[4][2];
#pragma unroll
      for (int kb = 0; kb < 4; ++kb) {
        const float p0 = __builtin_amdgcn_exp2f(accT4[kb][0]);
        const float p1 = __builtin_amdgcn_exp2f(accT4[kb][1]);
        const float p2 = __builtin_amdgcn_exp2f(accT4[kb][2]);
        const float p3 = __builtin_amdgcn_exp2f(accT4[kb][3]);
        l_part += (p0 + p1) + (p2 + p3);
        up[kb][0] = pk2(p0, p1);
        up[kb][1] = pk2(p2, p3);
      }

      // ---- O^T += V^T P^T ; P-frag is the lane's own data ----
#pragma unroll
      for (int ks2 = 0; ks2 < 2; ++ks2) {
        // slot (g,j): key = st*64 + ks2*32 + (j>=4)*16 + g*4 + (j&3)
        // = this lane's up[2*ks2 + (j>=4)][pair j&3] ; V stored to match.
        u32x4 wv;
        wv.x = up[2 * ks2][0];
        wv.y = up[2 * ks2][1];
        wv.z = up[2 * ks2 + 1][0];
        wv.w = up[2 * ks2 + 1][1];
        const short8 pa = __builtin_bit_cast(short8, wv);
        __builtin_amdgcn_s_setprio(1);
#pragma unroll
        for (int db = 0; db < 4; ++db) {
          const short8 vf = *(const short8*)
              &Vs[(db * 16 + c) * VP + st * 64 + ks2 * 32 + g * 8];
          accO4[db] = __builtin_amdgcn_mfma_f32_16x16x32_bf16(vf, pa, accO4[db], 0,0,0);
        }
        __builtin_amdgcn_s_setprio(0);
      }
    }
  }

  // ---- epilogue: reduce l across the 4 g-groups, normalize, store ----
  float l = l_part;
  l += __shfl_xor(l, 16);
  l += __shfl_xor(l, 32);
  const float inv = 1.f / l;
  const size_t rb = (size_t)qrow * Cc + h * Dd;
#pragma unroll
  for (int db = 0; db < 4; ++db) {
    const int d0 = db * 16 + g * 4;
    ushort4 uh, ul;
#pragma unroll
    for (int e = 0; e < 4; ++e) {
      const float o = accO4[db][e] * inv;
      const ushort hb = f2bf(o);
      ((ushort*)&uh)[e] = hb;
      ((ushort*)&ul)[e] = f2bf(o - bf2f(hb));
    }
    *(ushort4*)&ohi[rb + d0] = uh;
    *(ushort4*)&olo[rb + d0] = ul;
  }
}

// ---------------------------------------------------------------------------
extern "C" void kernel_launch(void* const* d_in, const int* in_sizes, int n_in,
                              void* d_out, int out_size, void* d_ws, size_t ws_size,
                              hipStream_t stream)
{
  const float* x     = (const float*)d_in[0];  // (B,N,C)
  const float* q     = (const float*)d_in[1];  // (TQ,C)
  const float* Wq    = (const float*)d_in[2];  // (C,C)
  const float* Wkv   = (const float*)d_in[3];  // (2C,C): rows [0,C)=Wk, [C,2C)=Wv
  const float* Wproj = (const float*)d_in[4];  // (C,C)
  const float* bproj = (const float*)d_in[5];  // (C)

  const int TQ = in_sizes[1] / Cc;   // 11776 (multiple of 128)
  const int BN = in_sizes[0] / Cc;   // 16384

  const float* Wv = Wkv + (size_t)Cc * Cc;     // rows [C,2C)

  const size_t szQ = (size_t)TQ * Cc * 2;
  const size_t szX = (size_t)BN * Cc * 2;

  // workspace carve (68 MB total)
  char* p = (char*)d_ws;
  ushort* q_hi  = (ushort*)p;  p += szQ;       // 12 MB
  ushort* k_bf  = (ushort*)p;  p += szX;       // 16 MB
  ushort* v_t   = (ushort*)p;  p += szX;       // 16 MB
  ushort* at_hi = (ushort*)p;  p += szQ;       // 12 MB
  ushort* at_lo = (ushort*)p;                  // 12 MB

  // 1) q_hi = bf16(C2SCALE * (q @ Wq^T)), 1-term, fused f32 staging
  mfma_nt2_kernel<2, 1, true, true><<<dim3(Cc/128, TQ/128), 256, 0, stream>>>(
      q, nullptr, Wq, nullptr, nullptr, nullptr, q_hi, Cc);
  // 2) k_bf = bf16(x @ Wk^T), 1-term
  mfma_nt2_kernel<1, 1, true, true><<<dim3(Cc/128, BN/128), 256, 0, stream>>>(
      x, nullptr, Wkv, nullptr, nullptr, nullptr, k_bf, Cc);
  // 3) v_t = bf16(Wv @ x^T), 1-term
  mfma_nt2_kernel<1, 1, true, true><<<dim3(BN/128, Cc/128), 256, 0, stream>>>(
      Wv, nullptr, x, nullptr, nullptr, nullptr, v_t, BN);
  // 4) attention: 16q/wave 16x16x32, lane-local P, conflict-free V staging
  attn_mfma11_kernel<<<dim3(64 * 15), 512, 0, stream>>>(
      q_hi, k_bf, v_t, at_hi, at_lo);
  // 5) out = attno @ Wproj^T + bproj, 3-term (A = bf16 hi/lo, B = f32 split)
  mfma_nt2_kernel<0, 3, false, true><<<dim3(Cc/128, TQ/128), 256, 0, stream>>>(
      at_hi, at_lo, Wproj, nullptr, bproj, (float*)d_out, nullptr, Cc);
}

// Round 16
// 186.418 us; speedup vs baseline: 1.0274x; 1.0274x over previous
//
#include <hip/hip_runtime.h>
#include <hip/hip_bf16.h>
#include <math.h>

// Problem constants (fixed by the reference):
constexpr int Cc = 512;   // channels
constexpr int Hh = 8;     // heads
constexpr int Dd = 64;    // head dim
constexpr int Nn = 2048;  // kv length
constexpr int Bb = 8;     // batch
constexpr int GK = 512;   // K dim of every GEMM here

typedef __attribute__((ext_vector_type(8))) short short8;
typedef __attribute__((ext_vector_type(4))) float f32x4;
typedef __attribute__((ext_vector_type(4))) unsigned int u32x4;
typedef __attribute__((ext_vector_type(2))) unsigned int u32x2;

// scale * log2(e) folded into Q at projection time
#define C2SCALE 0.1803368801f

static __device__ __forceinline__ ushort f2bf(float v) {
  __hip_bfloat16 h = __float2bfloat16(v);
  return *reinterpret_cast<ushort*>(&h);
}
static __device__ __forceinline__ float bf2f(ushort u) {
  __hip_bfloat16 h = *reinterpret_cast<__hip_bfloat16*>(&u);
  return __bfloat162float(h);
}
// pack two f32 -> u32 of two bf16 (f0 low, f1 high), RNE via f2bf
static __device__ __forceinline__ unsigned int pk2(float f0, float f1) {
  return (unsigned int)f2bf(f0) | ((unsigned int)f2bf(f1) << 16);
}

// ---------------------------------------------------------------------------
// MFMA GEMM with fused dtype handling (unchanged, proven): C = A B^T (+bias).
// ---------------------------------------------------------------------------
template <int MODE, int TERMS, bool AF32, bool BF32>
__global__ __launch_bounds__(256) void mfma_nt2_kernel(
    const void* __restrict__ A0p, const void* __restrict__ A1p,
    const void* __restrict__ B0p, const void* __restrict__ B1p,
    const float* __restrict__ bias, float* __restrict__ Cf,
    ushort* __restrict__ Chi, int Nc)
{
  __shared__ ushort lAh[128 * 32];
  __shared__ ushort lBh[128 * 32];
  __shared__ ushort lAl[TERMS == 3 ? 128 * 32 : 1];
  __shared__ ushort lBl[TERMS == 3 ? 128 * 32 : 1];

  const int tid = threadIdx.x;
  const int w = tid >> 6, lane = tid & 63;
  const int c = lane & 15, g = lane >> 4;
  const int wr = (w >> 1) * 64, wc = (w & 1) * 64;
  const int m0 = blockIdx.y * 128, n0 = blockIdx.x * 128;
  const int sr = tid >> 2;          // staging row 0..63
  const int sk = (tid & 3) * 8;     // staging k-offset (elements)

  short8 rAh[2], rAl[2], rBh[2], rBl[2];

  auto ldf32 = [&](const float* F, size_t idx, short8& h, short8& l) {
    const float4 f0 = *(const float4*)(F + idx);
    const float4 f1 = *(const float4*)(F + idx + 4);
    const float vv[8] = {f0.x, f0.y, f0.z, f0.w, f1.x, f1.y, f1.z, f1.w};
#pragma unroll
    for (int j = 0; j < 8; ++j) {
      const ushort hb = f2bf(vv[j]);
      ((ushort*)&h)[j] = hb;
      if (TERMS == 3) ((ushort*)&l)[j] = f2bf(vv[j] - bf2f(hb));
    }
  };

  auto loadA = [&](int k0) {
#pragma unroll
    for (int hf = 0; hf < 2; ++hf) {
      const size_t idx = (size_t)(m0 + sr + hf * 64) * GK + k0 + sk;
      if (AF32) {
        ldf32((const float*)A0p, idx, rAh[hf], rAl[hf]);
      } else {
        rAh[hf] = *(const short8*)((const ushort*)A0p + idx);
        if (TERMS == 3) rAl[hf] = *(const short8*)((const ushort*)A1p + idx);
      }
    }
  };
  auto loadB = [&](int k0) {
#pragma unroll
    for (int hf = 0; hf < 2; ++hf) {
      const size_t idx = (size_t)(n0 + sr + hf * 64) * GK + k0 + sk;
      if (BF32) {
        ldf32((const float*)B0p, idx, rBh[hf], rBl[hf]);
      } else {
        rBh[hf] = *(const short8*)((const ushort*)B0p + idx);
        if (TERMS == 3) rBl[hf] = *(const short8*)((const ushort*)B1p + idx);
      }
    }
  };

  f32x4 acc[4][4] = {};
  loadA(0);
  loadB(0);

  for (int k0 = 0; k0 < GK; k0 += 32) {
    __syncthreads();
    *(short8*)&lAh[sr * 32 + sk]        = rAh[0];
    *(short8*)&lAh[(sr + 64) * 32 + sk] = rAh[1];
    *(short8*)&lBh[sr * 32 + sk]        = rBh[0];
    *(short8*)&lBh[(sr + 64) * 32 + sk] = rBh[1];
    if (TERMS == 3) {
      *(short8*)&lAl[sr * 32 + sk]        = rAl[0];
      *(short8*)&lAl[(sr + 64) * 32 + sk] = rAl[1];
      *(short8*)&lBl[sr * 32 + sk]        = rBl[0];
      *(short8*)&lBl[(sr + 64) * 32 + sk] = rBl[1];
    }
    __syncthreads();
    if (k0 + 32 < GK) { loadA(k0 + 32); loadB(k0 + 32); }  // T14 issue-early

    short8 ah[4], al[4], bh[4], bl[4];
#pragma unroll
    for (int i = 0; i < 4; ++i) {
      const int ar = (wr + i * 16 + c) * 32 + g * 8;
      const int br = (wc + i * 16 + c) * 32 + g * 8;
      ah[i] = *(const short8*)&lAh[ar];
      bh[i] = *(const short8*)&lBh[br];
      if (TERMS == 3) {
        al[i] = *(const short8*)&lAl[ar];
        bl[i] = *(const short8*)&lBl[br];
      }
    }
#pragma unroll
    for (int mi = 0; mi < 4; ++mi)
#pragma unroll
      for (int nj = 0; nj < 4; ++nj) {
        if (TERMS == 3) {
          acc[mi][nj] = __builtin_amdgcn_mfma_f32_16x16x32_bf16(ah[mi], bl[nj], acc[mi][nj], 0,0,0);
          acc[mi][nj] = __builtin_amdgcn_mfma_f32_16x16x32_bf16(al[mi], bh[nj], acc[mi][nj], 0,0,0);
        }
        acc[mi][nj] = __builtin_amdgcn_mfma_f32_16x16x32_bf16(ah[mi], bh[nj], acc[mi][nj], 0,0,0);
      }
  }

#pragma unroll
  for (int mi = 0; mi < 4; ++mi) {
#pragma unroll
    for (int r = 0; r < 4; ++r) {
      const size_t rb = (size_t)(m0 + wr + mi * 16 + g * 4 + r) * Nc;
#pragma unroll
      for (int nj = 0; nj < 4; ++nj) {
        const int col = n0 + wc + nj * 16 + c;
        const float v = acc[mi][nj][r];
        if (MODE == 0) {
          Cf[rb + col] = v + bias[col];
        } else if (MODE == 1) {
          Chi[rb + col] = f2bf(v);
        } else {
          Chi[rb + col] = f2bf(v * C2SCALE);   // Q pre-scaled for exp2 domain
        }
      }
    }
  }
}

// ---------------------------------------------------------------------------
// Swapped-operand MFMA flash attention, 16x16x32, TWO 16-row q-sub-tiles per
// wave: every K/V LDS fragment read feeds 2 MFMAs (halves LDS-read traffic
// per FLOP back to the 32x32 ratio) while keeping the lane-local-P structure
// (zero cross-lane ops). Block = 128 q-rows x 1 (b,h), 4 waves x 32 q-rows.
// STATIC softmax in exp2 domain (Q pre-scaled); l-reduce deferred to epilogue.
// V sigma-permuted via global-fetch side (R15); 128-key staging chunks.
// ---------------------------------------------------------------------------
__global__ __launch_bounds__(256, 4) void attn_mfma12_kernel(
    const ushort* __restrict__ qhi,  // (TQ, C) bf16, pre-scaled by C2SCALE
    const ushort* __restrict__ kbf,  // (B*N, C) bf16
    const ushort* __restrict__ vtb,  // (C, B*N) bf16  (V^T)
    ushort* __restrict__ ohi,        // (TQ, C) bf16 hi
    ushort* __restrict__ olo)        // (TQ, C) bf16 lo
{
  // Q_LENGTHS = 1024 + 128*b ; cumulative offsets:
  constexpr int QOFF[8] = {0, 1024, 2176, 3456, 4864, 6400, 8064, 9856};

  const int lin = blockIdx.x;
  const int b  = lin & 7;            // lin%8=b -> batch pinned per XCD
  const int h  = (lin >> 3) & 7;
  const int qt = lin >> 6;

  const int Lb  = 1024 + 128 * b;
  const int off = QOFF[b];
  if (qt * 128 >= Lb) return;        // uniform; lengths are %128==0

  constexpr int KP = 72;             // K row stride (bf16)
  constexpr int VP = 136;            // V row stride (bf16)
  constexpr int NC = Nn / 128;       // 16 chunks of 128 keys
  __shared__ ushort Ks[128 * KP];    // [key][d]
  __shared__ ushort Vs[64 * VP];     // [d][sigma(key) within 128]

  const int tid = threadIdx.x;
  const int lane = tid & 63;
  const int w = tid >> 6;            // wave 0..3 -> q-rows [w*32, w*32+32)
  const int c = lane & 15;           // q (B-col) / key-row (A) / d-row (PV A)
  const int g = (lane >> 4) & 3;     // k-chunk selector

  // Q fragments for two 16-row sub-tiles t: rows w*32 + t*16 + c
  short8 qf[2][2];
  int qrow[2];
#pragma unroll
  for (int t = 0; t < 2; ++t) {
    qrow[t] = off + qt * 128 + w * 32 + t * 16 + c;
    const size_t base = (size_t)qrow[t] * Cc + h * Dd + g * 8;
    qf[t][0] = *(const short8*)(qhi + base);
    qf[t][1] = *(const short8*)(qhi + base + 32);
  }

  float l_part[2] = {0.f, 0.f};      // per-lane partial sums; reduced at end
  f32x4 accO4[2][4] = {};            // O^T per tile: rows d=db*16+g*4+r, col q=c

  const size_t kbase = (size_t)b * Nn * Cc + h * Dd;
  const size_t vbase = (size_t)h * Dd * (Bb * Nn) + (size_t)b * Nn;

  for (int ch = 0; ch < NC; ++ch) {
    __syncthreads();   // previous chunk's LDS reads complete
    // stage K: 128 keys x 128B (4 short8 per thread, 256 threads)
#pragma unroll
    for (int it = 0; it < 4; ++it) {
      const int i = tid + it * 256;
      const int row = i >> 3, c8 = (i & 7) * 8;
      *(short8*)&Ks[row * KP + c8] =
          *(const short8*)&kbf[kbase + (size_t)(ch * 128 + row) * Cc + c8];
    }
    // stage V: linear b128 LDS write; sigma^-1 applied to the GLOBAL fetch.
#pragma unroll
    for (int it = 0; it < 4; ++it) {
      const int i = tid + it * 256;
      const int row = i >> 4, c8 = (i & 15) * 8;
      const int kb1 = (c8 & ~31) | (((c8 >> 3) & 3) << 2);
      const size_t gb = vbase + (size_t)row * (Bb * Nn) + ch * 128;
      const u32x2 vlo = *(const u32x2*)&vtb[gb + kb1];
      const u32x2 vhi = *(const u32x2*)&vtb[gb + kb1 + 16];
      u32x4 vv;
      vv[0] = vlo[0]; vv[1] = vlo[1];
      vv[2] = vhi[0]; vv[3] = vhi[1];
      *(short8*)&Vs[row * VP + c8] = __builtin_bit_cast(short8, vv);
    }
    __syncthreads();

#pragma unroll
    for (int st = 0; st < 2; ++st) {
      // ---- S^T = K Q^T : one kf read feeds both q-sub-tiles ----
      f32x4 accT4[2][4] = {};
      __builtin_amdgcn_s_setprio(1);
#pragma unroll
      for (int ks2 = 0; ks2 < 2; ++ks2) {
#pragma unroll
        for (int kb = 0; kb < 4; ++kb) {
          const short8 kf = *(const short8*)
              &Ks[(st * 64 + kb * 16 + c) * KP + ks2 * 32 + g * 8];
          accT4[0][kb] = __builtin_amdgcn_mfma_f32_16x16x32_bf16(kf, qf[0][ks2], accT4[0][kb], 0,0,0);
          accT4[1][kb] = __builtin_amdgcn_mfma_f32_16x16x32_bf16(kf, qf[1][ks2], accT4[1][kb], 0,0,0);
        }
      }
      __builtin_amdgcn_s_setprio(0);

      // ---- static softmax: P = exp2(S), pack to bf16 pairs (lane-local) ----
      unsigned int up[2][4][2];
#pragma unroll
      for (int t = 0; t < 2; ++t)
#pragma unroll
        for (int kb = 0; kb < 4; ++kb) {
          const float p0 = __builtin_amdgcn_exp2f(accT4[t][kb][0]);
          const float p1 = __builtin_amdgcn_exp2f(accT4[t][kb][1]);
          const float p2 = __builtin_amdgcn_exp2f(accT4[t][kb][2]);
          const float p3 = __builtin_amdgcn_exp2f(accT4[t][kb][3]);
          l_part[t] += (p0 + p1) + (p2 + p3);
          up[t][kb][0] = pk2(p0, p1);
          up[t][kb][1] = pk2(p2, p3);
        }

      // ---- O^T += V^T P^T ; one vf read feeds both q-sub-tiles ----
#pragma unroll
      for (int ks2 = 0; ks2 < 2; ++ks2) {
        short8 pa[2];
#pragma unroll
        for (int t = 0; t < 2; ++t) {
          u32x4 wv;
          wv.x = up[t][2 * ks2][0];
          wv.y = up[t][2 * ks2][1];
          wv.z = up[t][2 * ks2 + 1][0];
          wv.w = up[t][2 * ks2 + 1][1];
          pa[t] = __builtin_bit_cast(short8, wv);
        }
        __builtin_amdgcn_s_setprio(1);
#pragma unroll
        for (int db = 0; db < 4; ++db) {
          const short8 vf = *(const short8*)
              &Vs[(db * 16 + c) * VP + st * 64 + ks2 * 32 + g * 8];
          accO4[0][db] = __builtin_amdgcn_mfma_f32_16x16x32_bf16(vf, pa[0], accO4[0][db], 0,0,0);
          accO4[1][db] = __builtin_amdgcn_mfma_f32_16x16x32_bf16(vf, pa[1], accO4[1][db], 0,0,0);
        }
        __builtin_amdgcn_s_setprio(0);
      }
    }
  }

  // ---- epilogue: reduce l across the 4 g-groups, normalize, store ----
#pragma unroll
  for (int t = 0; t < 2; ++t) {
    float l = l_part[t];
    l += __shfl_xor(l, 16);
    l += __shfl_xor(l, 32);
    const float inv = 1.f / l;
    const size_t rb = (size_t)qrow[t] * Cc + h * Dd;
#pragma unroll
    for (int db = 0; db < 4; ++db) {
      const int d0 = db * 16 + g * 4;
      ushort4 uh, ul;
#pragma unroll
      for (int e = 0; e < 4; ++e) {
        const float o = accO4[t][db][e] * inv;
        const ushort hb = f2bf(o);
        ((ushort*)&uh)[e] = hb;
        ((ushort*)&ul)[e] = f2bf(o - bf2f(hb));
      }
      *(ushort4*)&ohi[rb + d0] = uh;
      *(ushort4*)&olo[rb + d0] = ul;
    }
  }
}

// ---------------------------------------------------------------------------
extern "C" void kernel_launch(void* const* d_in, const int* in_sizes, int n_in,
                              void* d_out, int out_size, void* d_ws, size_t ws_size,
                              hipStream_t stream)
{
  const float* x     = (const float*)d_in[0];  // (B,N,C)
  const float* q     = (const float*)d_in[1];  // (TQ,C)
  const float* Wq    = (const float*)d_in[2];  // (C,C)
  const float* Wkv   = (const float*)d_in[3];  // (2C,C): rows [0,C)=Wk, [C,2C)=Wv
  const float* Wproj = (const float*)d_in[4];  // (C,C)
  const float* bproj = (const float*)d_in[5];  // (C)

  const int TQ = in_sizes[1] / Cc;   // 11776 (multiple of 128)
  const int BN = in_sizes[0] / Cc;   // 16384

  const float* Wv = Wkv + (size_t)Cc * Cc;     // rows [C,2C)

  const size_t szQ = (size_t)TQ * Cc * 2;
  const size_t szX = (size_t)BN * Cc * 2;

  // workspace carve (68 MB total)
  char* p = (char*)d_ws;
  ushort* q_hi  = (ushort*)p;  p += szQ;       // 12 MB
  ushort* k_bf  = (ushort*)p;  p += szX;       // 16 MB
  ushort* v_t   = (ushort*)p;  p += szX;       // 16 MB
  ushort* at_hi = (ushort*)p;  p += szQ;       // 12 MB
  ushort* at_lo = (ushort*)p;                  // 12 MB

  // 1) q_hi = bf16(C2SCALE * (q @ Wq^T)), 1-term, fused f32 staging
  mfma_nt2_kernel<2, 1, true, true><<<dim3(Cc/128, TQ/128), 256, 0, stream>>>(
      q, nullptr, Wq, nullptr, nullptr, nullptr, q_hi, Cc);
  // 2) k_bf = bf16(x @ Wk^T), 1-term
  mfma_nt2_kernel<1, 1, true, true><<<dim3(Cc/128, BN/128), 256, 0, stream>>>(
      x, nullptr, Wkv, nullptr, nullptr, nullptr, k_bf, Cc);
  // 3) v_t = bf16(Wv @ x^T), 1-term
  mfma_nt2_kernel<1, 1, true, true><<<dim3(BN/128, Cc/128), 256, 0, stream>>>(
      Wv, nullptr, x, nullptr, nullptr, nullptr, v_t, BN);
  // 4) attention: 2 q-sub-tiles/wave, lane-local P, shared K/V frag reads
  attn_mfma12_kernel<<<dim3(64 * 15), 256, 0, stream>>>(
      q_hi, k_bf, v_t, at_hi, at_lo);
  // 5) out = attno @ Wproj^T + bproj, 3-term (A = bf16 hi/lo, B = f32 split)
  mfma_nt2_kernel<0, 3, false, true><<<dim3(Cc/128, TQ/128), 256, 0, stream>>>(
      at_hi, at_lo, Wproj, nullptr, bproj, (float*)d_out, nullptr, Cc);
}